// Round 4
// baseline (477.594 us; speedup 1.0000x reference)
//
#include <hip/hip_runtime.h>

#define EPSN 1e-12f
#define SCALE_F 0.044194173824159216f  // 512^-0.5

typedef __bf16 bf16x8 __attribute__((ext_vector_type(8)));
typedef __bf16 bf16x4 __attribute__((ext_vector_type(4)));
typedef float  f32x4  __attribute__((ext_vector_type(4)));

// ---------------- prep: WqT/WkT bf16 [d][c] = W[c][d], LDS tile transpose ----------------
__global__ __launch_bounds__(256) void k_prep_t(const float* __restrict__ Wq,
                                                const float* __restrict__ Wk,
                                                __bf16* __restrict__ WqT,
                                                __bf16* __restrict__ WkT) {
  __shared__ float Tq[32][33], Tk[32][33];
  const int c0 = blockIdx.x * 32, d0 = blockIdx.y * 32;
  const int dx = threadIdx.x, cy = threadIdx.y;  // 32, 8
  #pragma unroll
  for (int p = 0; p < 4; ++p) {
    int c = cy + p * 8;
    Tq[c][dx] = Wq[(size_t)(c0 + c) * 512 + d0 + dx];
    Tk[c][dx] = Wk[(size_t)(c0 + c) * 512 + d0 + dx];
  }
  __syncthreads();
  #pragma unroll
  for (int p = 0; p < 4; ++p) {
    int d = cy + p * 8;
    WqT[(size_t)(d0 + d) * 512 + c0 + dx] = (__bf16)Tq[dx][d];
    WkT[(size_t)(d0 + d) * 512 + c0 + dx] = (__bf16)Tk[dx][d];
  }
}

// ---- prep: WcT[d][kk]: kk<512 -> (Wp@Wf)[kk][d]; kk>=512 -> Wf[kk-512][d]. bpf[d]=bp@Wf+bf
__global__ __launch_bounds__(512) void k_prep_w(const float* __restrict__ Wp,
                                                const float* __restrict__ Wf,
                                                const float* __restrict__ bp,
                                                const float* __restrict__ bfv,
                                                __bf16* __restrict__ WcT,
                                                float* __restrict__ bpf) {
  int kk = blockIdx.x;   // 512
  int d  = threadIdx.x;  // 512
  float a0 = 0.f, a1 = 0.f, a2 = 0.f, a3 = 0.f;
  for (int c = 0; c < 512; c += 4) {
    a0 = fmaf(Wp[kk * 512 + c],     Wf[(size_t)c * 512 + d],         a0);
    a1 = fmaf(Wp[kk * 512 + c + 1], Wf[(size_t)(c + 1) * 512 + d],   a1);
    a2 = fmaf(Wp[kk * 512 + c + 2], Wf[(size_t)(c + 2) * 512 + d],   a2);
    a3 = fmaf(Wp[kk * 512 + c + 3], Wf[(size_t)(c + 3) * 512 + d],   a3);
  }
  WcT[(size_t)d * 1024 + kk]       = (__bf16)((a0 + a1) + (a2 + a3));
  WcT[(size_t)d * 1024 + 512 + kk] = (__bf16)Wf[(size_t)kk * 512 + d];
  if (kk == 0) {
    float b0 = 0.f, b1 = 0.f;
    for (int c = 0; c < 512; c += 2) {
      b0 = fmaf(bp[c],     Wf[(size_t)c * 512 + d],       b0);
      b1 = fmaf(bp[c + 1], Wf[(size_t)(c + 1) * 512 + d], b1);
    }
    bpf[d] = b0 + b1 + bfv[d];
  }
}

// ---------------- fused Q+K GEMM + bias + row l2norm + pctx/pgsq partials ----------------
// Tile 64 tokens x 512 d. x-tile staged in LDS ONCE (1 barrier), then two
// barrier-free 16-step K-loops (Q pass, K pass) with register-prefetched B from L2.
__global__ __launch_bounds__(512) void k_qk(const float* __restrict__ x,
                                            const __bf16* __restrict__ WqT,
                                            const __bf16* __restrict__ WkT,
                                            const float* __restrict__ bq,
                                            const float* __restrict__ bk,
                                            const float* __restrict__ wg,
                                            __bf16* __restrict__ Qn,
                                            __bf16* __restrict__ Kn,
                                            float* __restrict__ pctx,
                                            float* __restrict__ pgsq) {
  __shared__ __bf16 Xs[64][520];             // 66,560 B; row = 65 16B-units (odd -> 2-way reads)
  __shared__ float red[8][64], redG[8][64];
  __shared__ float invv[64], gs[64];
  const int t = threadIdx.x;
  const int lane = t & 63, w = t >> 6;
  const int li = lane & 15, lq = lane >> 4;
  const int n0 = blockIdx.x * 64;
  const int b  = blockIdx.y;
  const int sn = t & 63, sc4 = (t >> 6) * 4;
  const bool nv = (n0 + sn < 784);
  const float* xp = x + ((size_t)b * 512 + sc4) * 784 + n0 + sn;

  // ---- stage full 64x512 x^T tile as bf16 (once) ----
  #pragma unroll
  for (int ks = 0; ks < 16; ++ks) {
    float v0 = nv ? xp[(size_t)(ks * 32 + 0) * 784] : 0.f;
    float v1 = nv ? xp[(size_t)(ks * 32 + 1) * 784] : 0.f;
    float v2 = nv ? xp[(size_t)(ks * 32 + 2) * 784] : 0.f;
    float v3 = nv ? xp[(size_t)(ks * 32 + 3) * 784] : 0.f;
    bf16x4 v; v[0] = (__bf16)v0; v[1] = (__bf16)v1; v[2] = (__bf16)v2; v[3] = (__bf16)v3;
    *(bf16x4*)&Xs[sn][ks * 32 + sc4] = v;
  }
  __syncthreads();

  auto gemmPass = [&](const __bf16* Wt, const float* bias, bool isQ, __bf16* dst) {
    const __bf16* wp = Wt + (size_t)(w * 64 + li) * 512 + lq * 8;
    f32x4 acc[4][4] = {};
    bf16x8 bA[4], bB[4];
    #pragma unroll
    for (int cb = 0; cb < 4; ++cb) bA[cb] = *(const bf16x8*)(wp + cb * 8192);
    // barrier-free K loop, B register-double-buffered
    #pragma unroll
    for (int ks = 0; ks < 16; ks += 2) {
      #pragma unroll
      for (int cb = 0; cb < 4; ++cb) bB[cb] = *(const bf16x8*)(wp + cb * 8192 + (ks + 1) * 32);
      bf16x8 af[4];
      #pragma unroll
      for (int rb = 0; rb < 4; ++rb) af[rb] = *(const bf16x8*)&Xs[rb * 16 + li][ks * 32 + lq * 8];
      #pragma unroll
      for (int cb = 0; cb < 4; ++cb)
        #pragma unroll
        for (int rb = 0; rb < 4; ++rb)
          acc[rb][cb] = __builtin_amdgcn_mfma_f32_16x16x32_bf16(af[rb], bA[cb], acc[rb][cb], 0, 0, 0);
      if (ks + 2 < 16) {
        #pragma unroll
        for (int cb = 0; cb < 4; ++cb) bA[cb] = *(const bf16x8*)(wp + cb * 8192 + (ks + 2) * 32);
      }
      #pragma unroll
      for (int rb = 0; rb < 4; ++rb) af[rb] = *(const bf16x8*)&Xs[rb * 16 + li][(ks + 1) * 32 + lq * 8];
      #pragma unroll
      for (int cb = 0; cb < 4; ++cb)
        #pragma unroll
        for (int rb = 0; rb < 4; ++rb)
          acc[rb][cb] = __builtin_amdgcn_mfma_f32_16x16x32_bf16(af[rb], bB[cb], acc[rb][cb], 0, 0, 0);
    }

    // ---- epilogue: bias, row sumsq (+ g-dot), normalize, store, pctx partial ----
    float bv[4], wv[4];
    #pragma unroll
    for (int cb = 0; cb < 4; ++cb) {
      int col = w * 64 + cb * 16 + li;
      bv[cb] = bias[col];
      wv[cb] = isQ ? wg[col] : 0.f;
    }
    #pragma unroll
    for (int rb = 0; rb < 4; ++rb)
      #pragma unroll
      for (int cb = 0; cb < 4; ++cb)
        #pragma unroll
        for (int j = 0; j < 4; ++j)
          acc[rb][cb][j] += bv[cb];
    #pragma unroll
    for (int rb = 0; rb < 4; ++rb)
      #pragma unroll
      for (int j = 0; j < 4; ++j) {
        float ss = 0.f, sg = 0.f;
        #pragma unroll
        for (int cb = 0; cb < 4; ++cb) {
          float v = acc[rb][cb][j];
          ss = fmaf(v, v, ss); sg = fmaf(v, wv[cb], sg);
        }
        ss += __shfl_xor(ss, 1); ss += __shfl_xor(ss, 2); ss += __shfl_xor(ss, 4); ss += __shfl_xor(ss, 8);
        sg += __shfl_xor(sg, 1); sg += __shfl_xor(sg, 2); sg += __shfl_xor(sg, 4); sg += __shfl_xor(sg, 8);
        if (li == 0) {
          int row = rb * 16 + lq * 4 + j;
          red[w][row] = ss; redG[w][row] = sg;
        }
      }
    __syncthreads();
    if (t < 64) {
      float ss = 0.f, sg = 0.f;
      #pragma unroll
      for (int wv2 = 0; wv2 < 8; ++wv2) { ss += red[wv2][t]; sg += redG[wv2][t]; }
      float iv = 1.f / fmaxf(sqrtf(ss), EPSN);
      invv[t] = iv;
      if (isQ) {
        float gv = (n0 + t < 784) ? sg * iv : 0.f;
        gs[t] = gv;
        float pg = gv * gv;
        pg += __shfl_xor(pg, 1);  pg += __shfl_xor(pg, 2);  pg += __shfl_xor(pg, 4);
        pg += __shfl_xor(pg, 8);  pg += __shfl_xor(pg, 16); pg += __shfl_xor(pg, 32);
        if (t == 0) pgsq[b * 13 + blockIdx.x] = pg;
      }
    }
    __syncthreads();
    float pc[4] = {0.f, 0.f, 0.f, 0.f};
    #pragma unroll
    for (int rb = 0; rb < 4; ++rb)
      #pragma unroll
      for (int j = 0; j < 4; ++j) {
        int row = rb * 16 + lq * 4 + j;
        if (n0 + row < 784) {
          float iv = invv[row];
          float gr = isQ ? gs[row] : 0.f;
          size_t base = ((size_t)b * 784 + n0 + row) * 512 + w * 64 + li;
          #pragma unroll
          for (int cb = 0; cb < 4; ++cb) {
            float qv = acc[rb][cb][j] * iv;
            dst[base + cb * 16] = (__bf16)qv;
            pc[cb] = fmaf(gr, qv, pc[cb]);
          }
        }
      }
    if (isQ) {
      #pragma unroll
      for (int cb = 0; cb < 4; ++cb) {
        pc[cb] += __shfl_xor(pc[cb], 16);
        pc[cb] += __shfl_xor(pc[cb], 32);
      }
      if (lq == 0) {
        #pragma unroll
        for (int cb = 0; cb < 4; ++cb)
          pctx[((size_t)b * 13 + blockIdx.x) * 512 + w * 64 + cb * 16 + li] = pc[cb];
      }
    }
  };

  gemmPass(WqT, bq, true,  Qn);
  gemmPass(WkT, bk, false, Kn);
}

// ---------------- combine: ctx[b,d] = alpha(b) * sum_tiles pctx ----------------
__global__ __launch_bounds__(512) void k_ctx2(const float* __restrict__ pctx,
                                              const float* __restrict__ pgsq,
                                              float* __restrict__ ctx) {
  const int b = blockIdx.x, t = threadIdx.x;
  float tot = 0.f;
  #pragma unroll
  for (int i = 0; i < 13; ++i) tot += pgsq[b * 13 + i];
  float alpha = SCALE_F / fmaxf(sqrtf(tot) * SCALE_F, EPSN);
  float s = 0.f;
  #pragma unroll
  for (int i = 0; i < 13; ++i) s += pctx[((size_t)b * 13 + i) * 512 + t];
  ctx[(size_t)b * 512 + t] = alpha * s;
}

// ---------------- final GEMM: out[b,d,n] = ([ctx*Kn | Qn] @ [Wpf;Wf] + bpf)^T ----------------
// Stage ctx*Kn tile (1 barrier) -> 16 barrier-free steps vs Wpf; restage Qn (2 barriers)
// -> 16 steps vs Wf. Direct coalesced f32x4 stores.
__global__ __launch_bounds__(512) void k_out(const __bf16* __restrict__ Qn,
                                             const __bf16* __restrict__ Kn,
                                             const float* __restrict__ ctx,
                                             const __bf16* __restrict__ WcT,
                                             const float* __restrict__ bpf,
                                             float* __restrict__ out) {
  __shared__ __bf16 Xs[64][520];
  const int t = threadIdx.x;
  const int lane = t & 63, w = t >> 6;
  const int li = lane & 15, lq = lane >> 4;
  const int n0 = blockIdx.x * 64;
  const int b  = blockIdx.y;
  const float* cxp = ctx + (size_t)b * 512;

  f32x4 acc[4][4] = {};

  auto mloop = [&](const __bf16* wp) {
    bf16x8 bA[4], bB[4];
    #pragma unroll
    for (int cb = 0; cb < 4; ++cb) bA[cb] = *(const bf16x8*)(wp + (size_t)cb * 16384);
    #pragma unroll
    for (int ks = 0; ks < 16; ks += 2) {
      #pragma unroll
      for (int cb = 0; cb < 4; ++cb) bB[cb] = *(const bf16x8*)(wp + (size_t)cb * 16384 + (ks + 1) * 32);
      bf16x8 af[4];
      #pragma unroll
      for (int rb = 0; rb < 4; ++rb) af[rb] = *(const bf16x8*)&Xs[rb * 16 + li][ks * 32 + lq * 8];
      #pragma unroll
      for (int cb = 0; cb < 4; ++cb)
        #pragma unroll
        for (int rb = 0; rb < 4; ++rb)
          acc[rb][cb] = __builtin_amdgcn_mfma_f32_16x16x32_bf16(af[rb], bA[cb], acc[rb][cb], 0, 0, 0);
      if (ks + 2 < 16) {
        #pragma unroll
        for (int cb = 0; cb < 4; ++cb) bA[cb] = *(const bf16x8*)(wp + (size_t)cb * 16384 + (ks + 2) * 32);
      }
      #pragma unroll
      for (int rb = 0; rb < 4; ++rb) af[rb] = *(const bf16x8*)&Xs[rb * 16 + li][(ks + 1) * 32 + lq * 8];
      #pragma unroll
      for (int cb = 0; cb < 4; ++cb)
        #pragma unroll
        for (int rb = 0; rb < 4; ++rb)
          acc[rb][cb] = __builtin_amdgcn_mfma_f32_16x16x32_bf16(af[rb], bB[cb], acc[rb][cb], 0, 0, 0);
    }
  };

  // ---- phase 1: A = ctx (.) Kn ----
  #pragma unroll
  for (int p = 0; p < 8; ++p) {
    int id = t + p * 512, n = id >> 6, c8 = id & 63;
    bf16x8 v = {};
    if (n0 + n < 784) v = *(const bf16x8*)(Kn + ((size_t)b * 784 + n0 + n) * 512 + c8 * 8);
    f32x4 c0 = *(const f32x4*)(cxp + c8 * 8);
    f32x4 c1 = *(const f32x4*)(cxp + c8 * 8 + 4);
    bf16x8 r;
    #pragma unroll
    for (int j = 0; j < 4; ++j) {
      r[j]     = (__bf16)((float)v[j]     * c0[j]);
      r[4 + j] = (__bf16)((float)v[4 + j] * c1[j]);
    }
    *(bf16x8*)&Xs[n][c8 * 8] = r;
  }
  __syncthreads();
  mloop(WcT + (size_t)(w * 64 + li) * 1024 + lq * 8);
  __syncthreads();

  // ---- phase 2: A = Qn ----
  #pragma unroll
  for (int p = 0; p < 8; ++p) {
    int id = t + p * 512, n = id >> 6, c8 = id & 63;
    bf16x8 v = {};
    if (n0 + n < 784) v = *(const bf16x8*)(Qn + ((size_t)b * 784 + n0 + n) * 512 + c8 * 8);
    *(bf16x8*)&Xs[n][c8 * 8] = v;
  }
  __syncthreads();
  mloop(WcT + (size_t)(w * 64 + li) * 1024 + 512 + lq * 8);

  // ---- epilogue: + bias, direct stores (lane -> 16B-contiguous n) ----
  float bv[4];
  #pragma unroll
  for (int cb = 0; cb < 4; ++cb) bv[cb] = bpf[w * 64 + cb * 16 + li];
  #pragma unroll
  for (int rb = 0; rb < 4; ++rb) {
    int nrow = n0 + rb * 16 + lq * 4;
    if (nrow < 784) {
      #pragma unroll
      for (int cb = 0; cb < 4; ++cb) {
        f32x4 v;
        #pragma unroll
        for (int j = 0; j < 4; ++j) v[j] = acc[rb][cb][j] + bv[cb];
        *(f32x4*)&out[((size_t)b * 512 + w * 64 + cb * 16 + li) * 784 + nrow] = v;
      }
    }
  }
}

extern "C" void kernel_launch(void* const* d_in, const int* in_sizes, int n_in,
                              void* d_out, int out_size, void* d_ws, size_t ws_size,
                              hipStream_t stream) {
  const float* x   = (const float*)d_in[0];
  const float* Wq  = (const float*)d_in[1];
  const float* bq  = (const float*)d_in[2];
  const float* Wk  = (const float*)d_in[3];
  const float* bk  = (const float*)d_in[4];
  const float* wg  = (const float*)d_in[5];
  const float* Wp  = (const float*)d_in[6];
  const float* bp  = (const float*)d_in[7];
  const float* Wf  = (const float*)d_in[8];
  const float* bfv = (const float*)d_in[9];
  float* out = (float*)d_out;
  char* ws = (char*)d_ws;

  const size_t SZQN = (size_t)64 * 784 * 512 * 2;   // 51,380,224 B
  __bf16* Qn   = (__bf16*)(ws);
  __bf16* Kn   = (__bf16*)(ws + SZQN);
  __bf16* WqT  = (__bf16*)(ws + 2 * SZQN);
  __bf16* WkT  = (__bf16*)(ws + 2 * SZQN + 524288);
  __bf16* WcT  = (__bf16*)(ws + 2 * SZQN + 2 * 524288);
  float*  bpf  = (float*) (ws + 2 * SZQN + 2 * 524288 + 1048576);
  float*  pctx = (float*) (ws + 2 * SZQN + 2 * 524288 + 1048576 + 2048);
  float*  pgsq = (float*) (ws + 2 * SZQN + 2 * 524288 + 1048576 + 2048 + 1703936);
  float*  ctx  = (float*) (ws + 2 * SZQN + 2 * 524288 + 1048576 + 2048 + 1703936 + 4096);
  // total ~106.8 MB

  k_prep_t<<<dim3(16, 16), dim3(32, 8), 0, stream>>>(Wq, Wk, WqT, WkT);
  k_prep_w<<<dim3(512),    dim3(512),   0, stream>>>(Wp, Wf, bp, bfv, WcT, bpf);
  k_qk    <<<dim3(13, 64), dim3(512),   0, stream>>>(x, WqT, WkT, bq, bk, wg, Qn, Kn, pctx, pgsq);
  k_ctx2  <<<dim3(64),     dim3(512),   0, stream>>>(pctx, pgsq, ctx);
  k_out   <<<dim3(13, 64), dim3(512),   0, stream>>>(Qn, Kn, ctx, WcT, bpf, out);
}

// Round 5
// 347.186 us; speedup vs baseline: 1.3756x; 1.3756x over previous
//
#include <hip/hip_runtime.h>

#define EPSN 1e-12f
#define SCALE_F 0.044194173824159216f  // 512^-0.5

typedef __bf16 bf16x8 __attribute__((ext_vector_type(8)));
typedef __bf16 bf16x4 __attribute__((ext_vector_type(4)));
typedef float  f32x4  __attribute__((ext_vector_type(4)));

__device__ __forceinline__ void gld16(const void* src, void* dst) {
  __builtin_amdgcn_global_load_lds(
      (const __attribute__((address_space(1))) unsigned int*)src,
      (__attribute__((address_space(3))) unsigned int*)dst, 16, 0, 0);
}

// ---------------- prep: WqT/WkT bf16 [d][c] = W[c][d], LDS tile transpose ----------------
__global__ __launch_bounds__(256) void k_prep_t(const float* __restrict__ Wq,
                                                const float* __restrict__ Wk,
                                                __bf16* __restrict__ WqT,
                                                __bf16* __restrict__ WkT) {
  __shared__ float Tq[32][33], Tk[32][33];
  const int c0 = blockIdx.x * 32, d0 = blockIdx.y * 32;
  const int dx = threadIdx.x, cy = threadIdx.y;  // 32, 8
  #pragma unroll
  for (int p = 0; p < 4; ++p) {
    int c = cy + p * 8;
    Tq[c][dx] = Wq[(size_t)(c0 + c) * 512 + d0 + dx];
    Tk[c][dx] = Wk[(size_t)(c0 + c) * 512 + d0 + dx];
  }
  __syncthreads();
  #pragma unroll
  for (int p = 0; p < 4; ++p) {
    int d = cy + p * 8;
    WqT[(size_t)(d0 + d) * 512 + c0 + dx] = (__bf16)Tq[dx][d];
    WkT[(size_t)(d0 + d) * 512 + c0 + dx] = (__bf16)Tk[dx][d];
  }
}

// ---- prep: WcT[d][kk]: kk<512 -> (Wp@Wf)[kk][d]; kk>=512 -> Wf[kk-512][d]. bpf[d]=bp@Wf+bf
__global__ __launch_bounds__(512) void k_prep_w(const float* __restrict__ Wp,
                                                const float* __restrict__ Wf,
                                                const float* __restrict__ bp,
                                                const float* __restrict__ bfv,
                                                __bf16* __restrict__ WcT,
                                                float* __restrict__ bpf) {
  int kk = blockIdx.x;   // 512
  int d  = threadIdx.x;  // 512
  float a0 = 0.f, a1 = 0.f, a2 = 0.f, a3 = 0.f;
  for (int c = 0; c < 512; c += 4) {
    a0 = fmaf(Wp[kk * 512 + c],     Wf[(size_t)c * 512 + d],         a0);
    a1 = fmaf(Wp[kk * 512 + c + 1], Wf[(size_t)(c + 1) * 512 + d],   a1);
    a2 = fmaf(Wp[kk * 512 + c + 2], Wf[(size_t)(c + 2) * 512 + d],   a2);
    a3 = fmaf(Wp[kk * 512 + c + 3], Wf[(size_t)(c + 3) * 512 + d],   a3);
  }
  WcT[(size_t)d * 1024 + kk]       = (__bf16)((a0 + a1) + (a2 + a3));
  WcT[(size_t)d * 1024 + 512 + kk] = (__bf16)Wf[(size_t)kk * 512 + d];
  if (kk == 0) {
    float b0 = 0.f, b1 = 0.f;
    for (int c = 0; c < 512; c += 2) {
      b0 = fmaf(bp[c],     Wf[(size_t)c * 512 + d],       b0);
      b1 = fmaf(bp[c + 1], Wf[(size_t)(c + 1) * 512 + d], b1);
    }
    bpf[d] = b0 + b1 + bfv[d];
  }
}

// ---------------- Q or K GEMM (z: 0=Q,1=K) + bias + row l2norm (+g, pctx for Q) ----------------
// m97 structure: tile 64 tok x 512 d, BK=32, single-buffered LDS (As 4KB regs-staged,
// Bs 32KB via global_load_lds), 2 barriers/step, __launch_bounds__(512,4) -> 2 blocks/CU.
__global__ __launch_bounds__(512, 4) void k_qk(const float* __restrict__ x,
                                               const __bf16* __restrict__ WqT,
                                               const __bf16* __restrict__ WkT,
                                               const float* __restrict__ bq,
                                               const float* __restrict__ bk,
                                               const float* __restrict__ wg,
                                               __bf16* __restrict__ Qn,
                                               __bf16* __restrict__ Kn,
                                               float* __restrict__ pctx,
                                               float* __restrict__ pgsq) {
  __shared__ __align__(1024) unsigned char stg[36864];   // As[64][32] 4KB | Bs[512][32] 32KB
  __shared__ float red[8][64], redG[8][64], invv[64], gs[64];
  const int t = threadIdx.x, lane = t & 63, w = t >> 6;
  const int li = lane & 15, lq = lane >> 4;
  const int n0 = blockIdx.x * 64, b = blockIdx.y, isK = blockIdx.z;
  const __bf16* Wt  = isK ? WkT : WqT;
  const float* bias = isK ? bk : bq;
  __bf16* dst       = isK ? Kn : Qn;

  // A staging: thread -> tok = t&63, c-quad cp = (t>>6)*4
  const int stok = t & 63, scp = (t >> 6) * 4;
  const bool nv = (n0 + stok < 784);
  const float* xp = x + ((size_t)b * 512 + scp) * 784 + n0 + stok;   // + (k0+j)*784
  // B staging: wave w regions r = w*4+i ; lane -> d-row r*16+(lane>>2), chunk lane&3
  const __bf16* wsrc = Wt + (size_t)((w * 4) * 16 + (lane >> 2)) * 512 + (lane & 3) * 8;

  f32x4 acc[4][4] = {};

  for (int ks = 0; ks < 16; ++ks) {
    const int k0 = ks * 32;
    // --- B via global_load_lds (async, 4 insts/wave) ---
    #pragma unroll
    for (int i = 0; i < 4; ++i) {
      int r = w * 4 + i;
      gld16(wsrc + (size_t)i * 16 * 512 + k0, (void*)(stg + 4096 + r * 1024));
    }
    // --- A: 4 coalesced f32 loads + cvt + one ds_write_b64 ---
    {
      float v0 = nv ? xp[(size_t)(k0 + 0) * 784] : 0.f;
      float v1 = nv ? xp[(size_t)(k0 + 1) * 784] : 0.f;
      float v2 = nv ? xp[(size_t)(k0 + 2) * 784] : 0.f;
      float v3 = nv ? xp[(size_t)(k0 + 3) * 784] : 0.f;
      bf16x4 v; v[0] = (__bf16)v0; v[1] = (__bf16)v1; v[2] = (__bf16)v2; v[3] = (__bf16)v3;
      *(bf16x4*)(stg + stok * 64 + scp * 2) = v;
    }
    __syncthreads();
    bf16x8 af[4];
    #pragma unroll
    for (int rb = 0; rb < 4; ++rb)
      af[rb] = *(const bf16x8*)(stg + (rb * 16 + li) * 64 + lq * 16);
    #pragma unroll
    for (int cb = 0; cb < 4; ++cb) {
      bf16x8 bf = *(const bf16x8*)(stg + 4096 + (w * 64 + cb * 16 + li) * 64 + lq * 16);
      #pragma unroll
      for (int rb = 0; rb < 4; ++rb)
        acc[rb][cb] = __builtin_amdgcn_mfma_f32_16x16x32_bf16(af[rb], bf, acc[rb][cb], 0, 0, 0);
    }
    __syncthreads();
  }

  // ---- epilogue: bias, row sumsq (+ g-dot for Q), normalize, store, pctx partial ----
  float bv[4], wv[4];
  #pragma unroll
  for (int cb = 0; cb < 4; ++cb) {
    int col = w * 64 + cb * 16 + li;
    bv[cb] = bias[col];
    wv[cb] = isK ? 0.f : wg[col];
  }
  #pragma unroll
  for (int rb = 0; rb < 4; ++rb)
    #pragma unroll
    for (int cb = 0; cb < 4; ++cb)
      #pragma unroll
      for (int j = 0; j < 4; ++j)
        acc[rb][cb][j] += bv[cb];
  #pragma unroll
  for (int rb = 0; rb < 4; ++rb)
    #pragma unroll
    for (int j = 0; j < 4; ++j) {
      float ss = 0.f, sg = 0.f;
      #pragma unroll
      for (int cb = 0; cb < 4; ++cb) {
        float v = acc[rb][cb][j];
        ss = fmaf(v, v, ss); sg = fmaf(v, wv[cb], sg);
      }
      ss += __shfl_xor(ss, 1); ss += __shfl_xor(ss, 2); ss += __shfl_xor(ss, 4); ss += __shfl_xor(ss, 8);
      sg += __shfl_xor(sg, 1); sg += __shfl_xor(sg, 2); sg += __shfl_xor(sg, 4); sg += __shfl_xor(sg, 8);
      if (li == 0) {
        int row = rb * 16 + lq * 4 + j;
        red[w][row] = ss; redG[w][row] = sg;
      }
    }
  __syncthreads();
  if (t < 64) {
    float ss = 0.f, sg = 0.f;
    #pragma unroll
    for (int wv2 = 0; wv2 < 8; ++wv2) { ss += red[wv2][t]; sg += redG[wv2][t]; }
    float iv = 1.f / fmaxf(sqrtf(ss), EPSN);
    invv[t] = iv;
    if (!isK) {
      float gv = (n0 + t < 784) ? sg * iv : 0.f;
      gs[t] = gv;
      float pg = gv * gv;
      pg += __shfl_xor(pg, 1);  pg += __shfl_xor(pg, 2);  pg += __shfl_xor(pg, 4);
      pg += __shfl_xor(pg, 8);  pg += __shfl_xor(pg, 16); pg += __shfl_xor(pg, 32);
      if (t == 0) pgsq[b * 13 + blockIdx.x] = pg;
    }
  }
  __syncthreads();
  float pc[4] = {0.f, 0.f, 0.f, 0.f};
  #pragma unroll
  for (int rb = 0; rb < 4; ++rb)
    #pragma unroll
    for (int j = 0; j < 4; ++j) {
      int row = rb * 16 + lq * 4 + j;
      if (n0 + row < 784) {
        float iv = invv[row];
        float gr = isK ? 0.f : gs[row];
        size_t base = ((size_t)b * 784 + n0 + row) * 512 + w * 64 + li;
        #pragma unroll
        for (int cb = 0; cb < 4; ++cb) {
          float qv = acc[rb][cb][j] * iv;
          dst[base + cb * 16] = (__bf16)qv;
          pc[cb] = fmaf(gr, qv, pc[cb]);
        }
      }
    }
  if (!isK) {
    #pragma unroll
    for (int cb = 0; cb < 4; ++cb) {
      pc[cb] += __shfl_xor(pc[cb], 16);
      pc[cb] += __shfl_xor(pc[cb], 32);
    }
    if (lq == 0) {
      #pragma unroll
      for (int cb = 0; cb < 4; ++cb)
        pctx[((size_t)b * 13 + blockIdx.x) * 512 + w * 64 + cb * 16 + li] = pc[cb];
    }
  }
}

// ---------------- combine: ctx[b,d] = alpha(b) * sum_tiles pctx ----------------
__global__ __launch_bounds__(512) void k_ctx2(const float* __restrict__ pctx,
                                              const float* __restrict__ pgsq,
                                              float* __restrict__ ctx) {
  const int b = blockIdx.x, t = threadIdx.x;
  float tot = 0.f;
  #pragma unroll
  for (int i = 0; i < 13; ++i) tot += pgsq[b * 13 + i];
  float alpha = SCALE_F / fmaxf(sqrtf(tot) * SCALE_F, EPSN);
  float s = 0.f;
  #pragma unroll
  for (int i = 0; i < 13; ++i) s += pctx[((size_t)b * 13 + i) * 512 + t];
  ctx[(size_t)b * 512 + t] = alpha * s;
}

// ---------------- Kn <- Kn (.) ctx[b]  (in-place; Kn is regenerated every launch) ----------------
__global__ __launch_bounds__(512) void k_kc(__bf16* __restrict__ Kn,
                                            const float* __restrict__ ctx) {
  const int b = blockIdx.y;
  const int chunk = blockIdx.x * 512 + threadIdx.x;   // 98*512 = 50176 chunks of 8
  const int row = chunk >> 6;                          // 0..783
  const int c8 = (chunk & 63) * 8;
  __bf16* p = Kn + ((size_t)b * 784 + row) * 512 + c8;
  const float* cp = ctx + b * 512 + c8;
  bf16x8 v = *(const bf16x8*)p;
  #pragma unroll
  for (int j = 0; j < 8; ++j) v[j] = (__bf16)((float)v[j] * cp[j]);
  *(bf16x8*)p = v;
}

// ---------------- final GEMM: out[b,d,n] = ([Kc | Qn] @ [Wpf;Wf] + bpf)^T ----------------
// m97 structure, fully async staging (A and B via global_load_lds), 32 K-steps.
__global__ __launch_bounds__(512, 4) void k_out(const __bf16* __restrict__ Qn,
                                                const __bf16* __restrict__ Kc,
                                                const __bf16* __restrict__ WcT,
                                                const float* __restrict__ bpf,
                                                float* __restrict__ out) {
  __shared__ __align__(1024) unsigned char stg[36864];   // As[64][32] 4KB | Bs[512][32] 32KB
  const int t = threadIdx.x, lane = t & 63, w = t >> 6;
  const int li = lane & 15, lq = lane >> 4;
  const int n0 = blockIdx.x * 64, b = blockIdx.y;
  // A: regions 0..3 -> tok rows r*16+(lane>>2); B: regions 4..35 -> d rows (r-4)*16+(lane>>2)
  size_t grow = (size_t)b * 784 + n0 + (lane >> 2);     // + r*16 more per region
  f32x4 acc[4][4] = {};

  for (int ks = 0; ks < 32; ++ks) {
    const int k0 = ks * 32;
    const __bf16* Arow = (ks < 16) ? Kc : Qn;
    const int kA = (ks < 16) ? k0 : k0 - 512;
    #pragma unroll
    for (int i = 0; i < 5; ++i) {
      int r = w + i * 8;
      if (r < 36) {
        void* dstl = (void*)(stg + r * 1024);
        if (r < 4) {
          size_t gr = grow + r * 16;
          if (gr > 50175) gr = 50175;
          gld16(Arow + gr * 512 + kA + (lane & 3) * 8, dstl);
        } else {
          int dr = (r - 4) * 16 + (lane >> 2);
          gld16(WcT + (size_t)dr * 1024 + k0 + (lane & 3) * 8, dstl);
        }
      }
    }
    __syncthreads();
    bf16x8 af[4];
    #pragma unroll
    for (int rb = 0; rb < 4; ++rb)
      af[rb] = *(const bf16x8*)(stg + (rb * 16 + li) * 64 + lq * 16);
    #pragma unroll
    for (int cb = 0; cb < 4; ++cb) {
      bf16x8 bf = *(const bf16x8*)(stg + 4096 + (w * 64 + cb * 16 + li) * 64 + lq * 16);
      #pragma unroll
      for (int rb = 0; rb < 4; ++rb)
        acc[rb][cb] = __builtin_amdgcn_mfma_f32_16x16x32_bf16(af[rb], bf, acc[rb][cb], 0, 0, 0);
    }
    __syncthreads();
  }

  // epilogue: + bias, direct f32x4 stores (nrow 4-aligned, batch-safe)
  float bv[4];
  #pragma unroll
  for (int cb = 0; cb < 4; ++cb) bv[cb] = bpf[w * 64 + cb * 16 + li];
  #pragma unroll
  for (int rb = 0; rb < 4; ++rb) {
    int nrow = n0 + rb * 16 + lq * 4;
    if (nrow < 784) {
      #pragma unroll
      for (int cb = 0; cb < 4; ++cb) {
        f32x4 v;
        #pragma unroll
        for (int j = 0; j < 4; ++j) v[j] = acc[rb][cb][j] + bv[cb];
        *(f32x4*)&out[((size_t)b * 512 + w * 64 + cb * 16 + li) * 784 + nrow] = v;
      }
    }
  }
}

extern "C" void kernel_launch(void* const* d_in, const int* in_sizes, int n_in,
                              void* d_out, int out_size, void* d_ws, size_t ws_size,
                              hipStream_t stream) {
  const float* x   = (const float*)d_in[0];
  const float* Wq  = (const float*)d_in[1];
  const float* bq  = (const float*)d_in[2];
  const float* Wk  = (const float*)d_in[3];
  const float* bk  = (const float*)d_in[4];
  const float* wg  = (const float*)d_in[5];
  const float* Wp  = (const float*)d_in[6];
  const float* bp  = (const float*)d_in[7];
  const float* Wf  = (const float*)d_in[8];
  const float* bfv = (const float*)d_in[9];
  float* out = (float*)d_out;
  char* ws = (char*)d_ws;

  const size_t SZQN = (size_t)64 * 784 * 512 * 2;   // 51,380,224 B
  __bf16* Qn   = (__bf16*)(ws);
  __bf16* Kn   = (__bf16*)(ws + SZQN);
  __bf16* WqT  = (__bf16*)(ws + 2 * SZQN);
  __bf16* WkT  = (__bf16*)(ws + 2 * SZQN + 524288);
  __bf16* WcT  = (__bf16*)(ws + 2 * SZQN + 2 * 524288);
  float*  bpf  = (float*) (ws + 2 * SZQN + 2 * 524288 + 1048576);
  float*  pctx = (float*) (ws + 2 * SZQN + 2 * 524288 + 1048576 + 2048);
  float*  pgsq = (float*) (ws + 2 * SZQN + 2 * 524288 + 1048576 + 2048 + 1703936);
  float*  ctx  = (float*) (ws + 2 * SZQN + 2 * 524288 + 1048576 + 2048 + 1703936 + 4096);
  // total ~106.8 MB

  k_prep_t<<<dim3(16, 16),    dim3(32, 8), 0, stream>>>(Wq, Wk, WqT, WkT);
  k_prep_w<<<dim3(512),       dim3(512),   0, stream>>>(Wp, Wf, bp, bfv, WcT, bpf);
  k_qk    <<<dim3(13, 64, 2), dim3(512),   0, stream>>>(x, WqT, WkT, bq, bk, wg, Qn, Kn, pctx, pgsq);
  k_ctx2  <<<dim3(64),        dim3(512),   0, stream>>>(pctx, pgsq, ctx);
  k_kc    <<<dim3(98, 64),    dim3(512),   0, stream>>>(Kn, ctx);
  k_out   <<<dim3(13, 64),    dim3(512),   0, stream>>>(Qn, Kn, WcT, bpf, out);
}